// Round 15
// baseline (103.165 us; speedup 1.0000x reference)
//
#include <hip/hip_runtime.h>

#define DEV __device__ __forceinline__

typedef __attribute__((ext_vector_type(8))) short bf16x8;
typedef __attribute__((ext_vector_type(4))) float f32x4;

constexpr int Nn = 4096, Dd = 256, Kk = 128;
constexpr int SEGS = 32;          // k1 segments per batch (128 rows each)
constexpr int CH2  = 8;           // k2 n-chunks per batch (512 rows each)
constexpr int NCH  = Nn / CH2;    // 512 rows per k2 block
constexpr int NSTEP = 64;         // k2 n-step

DEV unsigned short f2bf(float f) {
  unsigned int u = __builtin_bit_cast(unsigned int, f);
  u += 0x7FFFu + ((u >> 16) & 1u);          // RNE; inputs are finite
  return (unsigned short)(u >> 16);
}
DEV float bf2f(unsigned short h) {
  unsigned int u = (unsigned int)h << 16;
  return __builtin_bit_cast(float, u);
}

// k2 xT tile: row d = 128B (64 bf16 n-values). Swizzle 16B slot by
// hh(d) = (d&7)^((d>>4)&7)^(((d>>7)&1)<<1):
//  - staging writes (lane ln scatters d=ln*16+j): <=4-way (writes only)
//  - b128 frag reads (lanes d=base+ln):           <=2-way (free)
DEV unsigned lds2(unsigned d, unsigned nbyte) {
  unsigned hh = (d & 7u) ^ ((d >> 4) & 7u) ^ (((d >> 7) & 1u) << 1);
  return d * 128u + (nbyte ^ (hh << 4));
}

// k1 cbf LDS tile: row k = 512B (256 bf16 d-values). XOR byte bits 4-6 by
// (row&7): the 16-row b128 frag read spreads across the 8 bank-quads.
DEV unsigned ldsc(unsigned row, unsigned byteInRow) {
  return row * 512u + (byteInRow ^ ((row & 7u) << 4));
}

// k1 W-transpose tile: row k = 256B (128 bf16 n-values). h includes k bit3 so
// the 4 lane-groups (k = f*16 + g*4 + r) land on 4 distinct 16B slots ->
// scalar write pass conflict-free; row-contiguous read pass free.
DEV unsigned ldsw(unsigned k, unsigned nbyte) {
  unsigned h = (k & 7u) ^ (((k >> 3) & 1u) << 1);
  return k * 256u + (nbyte ^ (h << 4));
}

__global__ void enc_prep(const float* __restrict__ cw, const float* __restrict__ sc,
                         unsigned short* __restrict__ cbf, float2* __restrict__ tab,
                         float* __restrict__ Wsumg) {
  int k = blockIdx.x, l = threadIdx.x;          // 128 blocks x 64 threads
  float4 u = *(const float4*)(cw + k * Dd + l * 4);
  float s2 = u.x * u.x + u.y * u.y + u.z * u.z + u.w * u.w;
  #pragma unroll
  for (int o = 1; o < 64; o <<= 1) s2 += __shfl_xor(s2, o);
  unsigned short* dst = cbf + k * Dd + l * 4;
  dst[0] = f2bf(u.x); dst[1] = f2bf(u.y); dst[2] = f2bf(u.z); dst[3] = f2bf(u.w);
  if (l == 0) { float s = sc[k]; tab[k] = make_float2(s * s2, 2.0f * s); }
  if (l < 32) Wsumg[l * Kk + k] = 0.0f;         // zero Wsum[b=l][k]
}

// ---------------- k1: W^T producer. Full-row x prefetch; cbf in swizzled LDS;
// W-tile transposed through LDS -> coalesced dwordx4 stores; per-block Wsum
// partials accumulated during the store pass and atomically added to Wsumg.
__global__ __launch_bounds__(512, 1) void enc_w(
    const float* __restrict__ x, const unsigned short* __restrict__ cbf,
    const float2* __restrict__ tab, unsigned short* __restrict__ Wt,
    float* __restrict__ Wsumg) {
  __shared__ __align__(16) char cL[65536];       // cbf tile; reused as W staging
  __shared__ float2 tabL[Kk];
  __shared__ float WsL[Kk];
  const int tid = threadIdx.x;
  const int w  = tid >> 6;             // wave 0..7
  const int l  = tid & 63;
  const int g  = l >> 4;               // 16-lane group 0..3
  const int ln = l & 15;

  // stage cbf -> swizzled LDS: thread i copies 128B (row i/4, quarter i%4)
  {
    const int r = tid >> 2, part = tid & 3;
    const char* src = (const char*)cbf + r * 512 + part * 128;
    #pragma unroll
    for (int j = 0; j < 8; ++j) {
      float4 v = *(const float4*)(src + j * 16);
      *(float4*)(cL + ldsc((unsigned)r, (unsigned)(part * 128 + j * 16))) = v;
    }
  }
  if (tid < Kk) { tabL[tid] = tab[tid]; WsL[tid] = 0.0f; }
  __syncthreads();

  const int b   = blockIdx.x >> 5;     // 32 batches x 32 segments
  const int seg = blockIdx.x & 31;
  const int nrow = seg * 128 + w * 16 + ln;            // row within batch
  const float* xrow = x + ((size_t)b * Nn + nrow) * Dd;

  f32x4 s1[8];
  const f32x4 zero4 = {0.f, 0.f, 0.f, 0.f};
  #pragma unroll
  for (int f = 0; f < 8; ++f) s1[f] = zero4;
  float x2p = 0.f;

  // full-row prefetch: 16 independent loads in flight before any consumption
  float4 pu[8][2];
  #pragma unroll
  for (int p = 0; p < 8; ++p) {
    pu[p][0] = *(const float4*)(xrow + p * 32 + g * 8);
    pu[p][1] = *(const float4*)(xrow + p * 32 + g * 8 + 4);
  }

  #pragma unroll
  for (int ks = 0; ks < 8; ++ks) {
    float4 u0 = pu[ks][0], u1 = pu[ks][1];
    x2p += u0.x*u0.x + u0.y*u0.y + u0.z*u0.z + u0.w*u0.w
         + u1.x*u1.x + u1.y*u1.y + u1.z*u1.z + u1.w*u1.w;
    bf16x8 xv;
    xv[0] = (short)f2bf(u0.x); xv[1] = (short)f2bf(u0.y);
    xv[2] = (short)f2bf(u0.z); xv[3] = (short)f2bf(u0.w);
    xv[4] = (short)f2bf(u1.x); xv[5] = (short)f2bf(u1.y);
    xv[6] = (short)f2bf(u1.z); xv[7] = (short)f2bf(u1.w);
    const unsigned colb = (unsigned)(ks * 64 + g * 16);
    #pragma unroll
    for (int f = 0; f < 8; ++f) {
      bf16x8 a = *(const bf16x8*)(cL + ldsc((unsigned)(f * 16 + ln), colb));
      s1[f] = __builtin_amdgcn_mfma_f32_16x16x32_bf16(a, xv, s1[f], 0, 0, 0);
    }
  }

  x2p += __shfl_xor(x2p, 16); x2p += __shfl_xor(x2p, 32);
  const float hx2 = 0.5f * x2p;
  float ssum = 0.f;
  #pragma unroll
  for (int f = 0; f < 8; ++f) {
    #pragma unroll
    for (int r = 0; r < 4; ++r) {
      const float2 ab = tabL[f * 16 + g * 4 + r];
      const float ev = __expf(ab.x + ab.y * (hx2 - s1[f][r]));
      s1[f][r] = ev;
      ssum += ev;
    }
  }
  ssum += __shfl_xor(ssum, 16); ssum += __shfl_xor(ssum, 32);
  const float rinv = 1.0f / ssum;

  // transpose W through LDS (reuse cL: all cbf reads are done)
  __syncthreads();
  #pragma unroll
  for (int f = 0; f < 8; ++f) {
    #pragma unroll
    for (int r = 0; r < 4; ++r) {
      const int cwi = f * 16 + g * 4 + r;
      *(unsigned short*)(cL + ldsw((unsigned)cwi, (unsigned)((w * 16 + ln) * 2)))
          = f2bf(s1[f][r] * rinv);
    }
  }
  __syncthreads();
  // coalesced store pass; fold per-k Wsum partials out of the same registers
  {
    char* wq = (char*)(Wt + (size_t)b * Kk * Nn + seg * 128);
    #pragma unroll
    for (int j = 0; j < 4; ++j) {
      const unsigned o = (unsigned)tid * 16u + (unsigned)j * 8192u;
      const unsigned k = o >> 8, nb = o & 255u;
      float4 v = *(const float4*)(cL + ldsw(k, nb));
      *(float4*)(wq + (size_t)k * (Nn * 2) + nb) = v;
      const unsigned short* hv = (const unsigned short*)&v;
      float wsp = 0.f;
      #pragma unroll
      for (int q = 0; q < 8; ++q) wsp += bf2f(hv[q]);
      atomicAdd(&WsL[k], wsp);
    }
  }
  __syncthreads();
  if (tid < Kk) atomicAdd(&Wsumg[b * Kk + tid], WsL[tid]);
}

// ---------------- k2: Ep_chunk[k][d] = sum_n W^T[k][n] x[n][d]  (raw partials;
// the -Wsum*c correction is applied once in the reduce). Double-buffered LDS xT,
// issue-early/write-late staging, W frags prefetched one step ahead.
template<int PM>
__global__ __launch_bounds__(1024) void enc_e(
    const float* __restrict__ x, const unsigned short* __restrict__ Wt,
    unsigned short* __restrict__ Ep, float* __restrict__ out) {
  __shared__ __align__(16) char xs[2 * 32768];   // xT [256 d][64 n] bf16, dbuf

  const int tid = threadIdx.x;
  const int w  = tid >> 6;             // wave 0..15
  const int l  = tid & 63;
  const int g  = l >> 4;
  const int ln = l & 15;
  const int wr = w >> 2, wc = w & 3;   // 4x4 wave grid over E(128k x 256d)
  const int b  = blockIdx.x >> 3, ch = blockIdx.x & 7;

  const float* xb = x + ((size_t)b * Nn + ch * NCH) * Dd;
  const unsigned short* Wb = Wt + (size_t)b * Kk * Nn + ch * NCH;

  // staging role: row n_loc = w*4+g (0..63), d-slice = ln*16..+15 (16 floats)
  const int srow = w * 4 + g;
  const int sd0  = ln * 16;

  f32x4 acc[2][4];
  const f32x4 zero4 = {0.f, 0.f, 0.f, 0.f};
  #pragma unroll
  for (int mi = 0; mi < 2; ++mi)
    #pragma unroll
    for (int ni = 0; ni < 4; ++ni) acc[mi][ni] = zero4;

  // prologue: stage step 0 into buf 0; prefetch step 0's W frags
  {
    const float* p = xb + (size_t)srow * Dd + sd0;
    float4 u0 = *(const float4*)(p + 0), u1 = *(const float4*)(p + 4);
    float4 u2 = *(const float4*)(p + 8), u3 = *(const float4*)(p + 12);
    const float uu[16] = {u0.x,u0.y,u0.z,u0.w, u1.x,u1.y,u1.z,u1.w,
                          u2.x,u2.y,u2.z,u2.w, u3.x,u3.y,u3.z,u3.w};
    #pragma unroll
    for (int j = 0; j < 16; ++j)
      *(unsigned short*)(xs + lds2((unsigned)(sd0 + j), (unsigned)(srow * 2))) = f2bf(uu[j]);
  }
  bf16x8 wf[2][2];   // [ks2][mi] current step's W fragments
  #pragma unroll
  for (int ks2 = 0; ks2 < 2; ++ks2)
    #pragma unroll
    for (int mi = 0; mi < 2; ++mi)
      wf[ks2][mi] = *(const bf16x8*)(Wb + (size_t)(wr * 32 + mi * 16 + ln) * Nn
                                        + ks2 * 32 + g * 8);
  __syncthreads();

  int cur = 0;
  for (int s = 0; s < CH2; ++s) {          // 8 n-steps of 64
    // issue next step's x loads AND W-frag loads before compute
    float4 n0, n1, n2, n3;
    bf16x8 wn[2][2];
    if (s + 1 < CH2) {
      const float* p = xb + (size_t)((s + 1) * NSTEP + srow) * Dd + sd0;
      n0 = *(const float4*)(p + 0); n1 = *(const float4*)(p + 4);
      n2 = *(const float4*)(p + 8); n3 = *(const float4*)(p + 12);
      #pragma unroll
      for (int ks2 = 0; ks2 < 2; ++ks2)
        #pragma unroll
        for (int mi = 0; mi < 2; ++mi)
          wn[ks2][mi] = *(const bf16x8*)(Wb + (size_t)(wr * 32 + mi * 16 + ln) * Nn
                                            + (s + 1) * NSTEP + ks2 * 32 + g * 8);
    }

    const char* xcur = xs + (cur << 15);
    #pragma unroll
    for (int ks2 = 0; ks2 < 2; ++ks2) {
      bf16x8 bg[4];
      #pragma unroll
      for (int ni = 0; ni < 4; ++ni)
        bg[ni] = *(const bf16x8*)(xcur + lds2((unsigned)(wc * 64 + ni * 16 + ln),
                                              (unsigned)((ks2 * 32 + g * 8) * 2)));
      #pragma unroll
      for (int mi = 0; mi < 2; ++mi)
        #pragma unroll
        for (int ni = 0; ni < 4; ++ni)
          acc[mi][ni] = __builtin_amdgcn_mfma_f32_16x16x32_bf16(wf[ks2][mi], bg[ni], acc[mi][ni], 0, 0, 0);
    }

    if (s + 1 < CH2) {
      // write-late: LDS writes to the opposite buffer (no reader this step)
      char* xn = xs + ((cur ^ 1) << 15);
      const float uu[16] = {n0.x,n0.y,n0.z,n0.w, n1.x,n1.y,n1.z,n1.w,
                            n2.x,n2.y,n2.z,n2.w, n3.x,n3.y,n3.z,n3.w};
      #pragma unroll
      for (int j = 0; j < 16; ++j)
        *(unsigned short*)(xn + lds2((unsigned)(sd0 + j), (unsigned)(srow * 2))) = f2bf(uu[j]);
      #pragma unroll
      for (int ks2 = 0; ks2 < 2; ++ks2)
        #pragma unroll
        for (int mi = 0; mi < 2; ++mi)
          wf[ks2][mi] = wn[ks2][mi];
    }
    __syncthreads();   // single barrier per step
    cur ^= 1;
  }

  // epilogue: bare bf16 partial store (correction applied in reduce)
  #pragma unroll
  for (int mi = 0; mi < 2; ++mi) {
    #pragma unroll
    for (int r = 0; r < 4; ++r) {
      const int k = wr * 32 + mi * 16 + g * 4 + r;
      #pragma unroll
      for (int ni = 0; ni < 4; ++ni) {
        const int d = wc * 64 + ni * 16 + ln;
        if (PM == 0) {
          Ep[(size_t)blockIdx.x * (Kk * Dd) + k * Dd + d] = f2bf(acc[mi][ni][r]);
        } else {
          atomicAdd(out + (size_t)b * (Kk * Dd) + k * Dd + d, acc[mi][ni][r]);
        }
      }
    }
  }
}

// ---------------- k3: out = sum over 8 bf16 chunk-partials - Wsum[b][k]*cw[k][d]
__global__ __launch_bounds__(256, 1) void enc_reduce_b16(
    const unsigned short* __restrict__ Ep, const float* __restrict__ Wsumg,
    const float* __restrict__ cw, float* __restrict__ out) {
  const size_t i = ((size_t)blockIdx.x * 256 + threadIdx.x) * 16;
  const int b   = (int)(i / (Kk * Dd));
  const int rem = (int)(i % (Kk * Dd));
  const int k   = rem >> 8;                       // Dd = 256
  const unsigned short* p = Ep + (size_t)b * CH2 * (Kk * Dd) + rem;
  const float wsv = Wsumg[b * Kk + k];
  float sx[16];
  #pragma unroll
  for (int j = 0; j < 16; ++j) sx[j] = 0.f;
  #pragma unroll
  for (int c = 0; c < CH2; ++c) {
    const ushort4* q = (const ushort4*)(p + (size_t)c * (Kk * Dd));
    ushort4 v0 = q[0], v1 = q[1], v2 = q[2], v3 = q[3];
    sx[0]  += bf2f(v0.x); sx[1]  += bf2f(v0.y); sx[2]  += bf2f(v0.z); sx[3]  += bf2f(v0.w);
    sx[4]  += bf2f(v1.x); sx[5]  += bf2f(v1.y); sx[6]  += bf2f(v1.z); sx[7]  += bf2f(v1.w);
    sx[8]  += bf2f(v2.x); sx[9]  += bf2f(v2.y); sx[10] += bf2f(v2.z); sx[11] += bf2f(v2.w);
    sx[12] += bf2f(v3.x); sx[13] += bf2f(v3.y); sx[14] += bf2f(v3.z); sx[15] += bf2f(v3.w);
  }
  const float* cp = cw + (size_t)rem;
  float4 c0 = *(const float4*)(cp + 0), c1 = *(const float4*)(cp + 4);
  float4 c2 = *(const float4*)(cp + 8), c3 = *(const float4*)(cp + 12);
  float4* o = (float4*)(out + i);
  o[0] = make_float4(sx[0] - wsv * c0.x, sx[1] - wsv * c0.y, sx[2] - wsv * c0.z, sx[3] - wsv * c0.w);
  o[1] = make_float4(sx[4] - wsv * c1.x, sx[5] - wsv * c1.y, sx[6] - wsv * c1.z, sx[7] - wsv * c1.w);
  o[2] = make_float4(sx[8] - wsv * c2.x, sx[9] - wsv * c2.y, sx[10] - wsv * c2.z, sx[11] - wsv * c2.w);
  o[3] = make_float4(sx[12] - wsv * c3.x, sx[13] - wsv * c3.y, sx[14] - wsv * c3.z, sx[15] - wsv * c3.w);
}

// fallback-path fixup: out[i] -= Wsum[b][k]*cw[k][d]
__global__ __launch_bounds__(256, 1) void enc_fix(
    const float* __restrict__ Wsumg, const float* __restrict__ cw,
    float* __restrict__ out) {
  const size_t i = ((size_t)blockIdx.x * 256 + threadIdx.x) * 16;
  const int b   = (int)(i / (Kk * Dd));
  const int rem = (int)(i % (Kk * Dd));
  const int k   = rem >> 8;
  const float wsv = Wsumg[b * Kk + k];
  float* o = out + i;
  const float* cp = cw + (size_t)rem;
  #pragma unroll
  for (int j = 0; j < 16; ++j) o[j] -= wsv * cp[j];
}

extern "C" void kernel_launch(void* const* d_in, const int* in_sizes, int n_in,
                              void* d_out, int out_size, void* d_ws, size_t ws_size,
                              hipStream_t stream) {
  const float* x  = (const float*)d_in[0];   // (32, 4096, 256)
  const float* cw = (const float*)d_in[1];   // (128, 256)
  const float* sc = (const float*)d_in[2];   // (128,)
  float* out = (float*)d_out;                // (32, 128, 256)

  unsigned short* cbf = (unsigned short*)d_ws;                      // 64KB
  float2* tab = (float2*)((char*)d_ws + 65536);                     // 1KB
  float*  Wsumg = (float*)((char*)d_ws + 66560);                    // 16KB [b][k]
  unsigned short* Wt = (unsigned short*)((char*)d_ws + 82944);      // 33.55MB W^T bf16
  unsigned short* Ep = (unsigned short*)((char*)d_ws + 82944 + (size_t)32 * Kk * Nn * 2); // 16.8MB bf16
  const size_t KD = (size_t)Kk * Dd;
  const size_t needFull = 82944 + (size_t)32 * Kk * Nn * 2 + (size_t)32 * CH2 * KD * 2;
  const size_t needAtm  = 82944 + (size_t)32 * Kk * Nn * 2;

  enc_prep<<<dim3(Kk), dim3(64), 0, stream>>>(cw, sc, cbf, tab, Wsumg);
  enc_w<<<dim3(32 * SEGS), dim3(512), 0, stream>>>(x, cbf, tab, Wt, Wsumg);

  if (ws_size >= needFull) {
    enc_e<0><<<dim3(32 * CH2), dim3(1024), 0, stream>>>(x, Wt, Ep, nullptr);
    enc_reduce_b16<<<dim3(256), dim3(256), 0, stream>>>(Ep, Wsumg, cw, out);
  } else if (ws_size >= needAtm) {
    hipMemsetAsync(d_out, 0, (size_t)out_size * sizeof(float), stream);
    enc_e<2><<<dim3(32 * CH2), dim3(1024), 0, stream>>>(x, Wt, nullptr, out);
    enc_fix<<<dim3(256), dim3(256), 0, stream>>>(Wsumg, cw, out);
  }
}

// Round 16
// 98.042 us; speedup vs baseline: 1.0522x; 1.0522x over previous
//
#include <hip/hip_runtime.h>

#define DEV __device__ __forceinline__

typedef __attribute__((ext_vector_type(8))) short bf16x8;
typedef __attribute__((ext_vector_type(4))) float f32x4;

constexpr int Nn = 4096, Dd = 256, Kk = 128;
constexpr int SEGS = 32;          // k1 segments per batch (128 rows each)
constexpr int CH2  = 8;           // k2 n-chunks per batch (512 rows each)
constexpr int NCH  = Nn / CH2;    // 512 rows per k2 block
constexpr int NSTEP = 64;         // k2 n-step

DEV unsigned short f2bf(float f) {
  unsigned int u = __builtin_bit_cast(unsigned int, f);
  u += 0x7FFFu + ((u >> 16) & 1u);          // RNE; inputs are finite
  return (unsigned short)(u >> 16);
}
DEV float bf2f(unsigned short h) {
  unsigned int u = (unsigned int)h << 16;
  return __builtin_bit_cast(float, u);
}

// k2 xT tile: row d = 128B (64 bf16 n-values). Swizzle 16B slot by
// hh(d) = (d&7)^((d>>4)&7)^(((d>>7)&1)<<1):
//  - staging writes (lane ln scatters d=ln*16+j): <=4-way (writes only)
//  - b128 frag reads (lanes d=base+ln):           <=2-way (free)
DEV unsigned lds2(unsigned d, unsigned nbyte) {
  unsigned hh = (d & 7u) ^ ((d >> 4) & 7u) ^ (((d >> 7) & 1u) << 1);
  return d * 128u + (nbyte ^ (hh << 4));
}

// k1 cbf LDS tile: row k = 512B (256 bf16 d-values). XOR byte bits 4-6 by
// (row&7): the 16-row b128 frag read spreads across the 8 bank-quads.
DEV unsigned ldsc(unsigned row, unsigned byteInRow) {
  return row * 512u + (byteInRow ^ ((row & 7u) << 4));
}

// k1 W-transpose tile: row k = 256B (128 bf16 n-values). h includes k bit3 so
// the 4 lane-groups (k = f*16 + g*4 + r) land on 4 distinct 16B slots ->
// scalar write pass conflict-free; row-contiguous read pass free.
DEV unsigned ldsw(unsigned k, unsigned nbyte) {
  unsigned h = (k & 7u) ^ (((k >> 3) & 1u) << 1);
  return k * 256u + (nbyte ^ (h << 4));
}

__global__ void enc_prep(const float* __restrict__ cw, const float* __restrict__ sc,
                         unsigned short* __restrict__ cbf, float2* __restrict__ tab) {
  int k = blockIdx.x, l = threadIdx.x;          // 128 blocks x 64 threads
  float4 u = *(const float4*)(cw + k * Dd + l * 4);
  float s2 = u.x * u.x + u.y * u.y + u.z * u.z + u.w * u.w;
  #pragma unroll
  for (int o = 1; o < 64; o <<= 1) s2 += __shfl_xor(s2, o);
  unsigned short* dst = cbf + k * Dd + l * 4;
  dst[0] = f2bf(u.x); dst[1] = f2bf(u.y); dst[2] = f2bf(u.z); dst[3] = f2bf(u.w);
  if (l == 0) { float s = sc[k]; tab[k] = make_float2(s * s2, 2.0f * s); }
}

// ---------------- k1: W^T producer. Distance-4 rotating x prefetch pinned by
// sched_barrier(0) per iteration (hipcc otherwise sinks the loads to their
// uses — r15 showed VGPR=68, i.e. zero prefetch depth). cbf in swizzled LDS;
// W transposed through LDS -> coalesced dwordx4 stores. No Wsum here.
__global__ __launch_bounds__(512, 1) void enc_w(
    const float* __restrict__ x, const unsigned short* __restrict__ cbf,
    const float2* __restrict__ tab, unsigned short* __restrict__ Wt) {
  __shared__ __align__(16) char cL[65536];       // cbf tile; reused as W staging
  __shared__ float2 tabL[Kk];
  const int tid = threadIdx.x;
  const int w  = tid >> 6;             // wave 0..7
  const int l  = tid & 63;
  const int g  = l >> 4;               // 16-lane group 0..3
  const int ln = l & 15;

  // stage cbf -> swizzled LDS: thread i copies 128B (row i/4, quarter i%4)
  {
    const int r = tid >> 2, part = tid & 3;
    const char* src = (const char*)cbf + r * 512 + part * 128;
    #pragma unroll
    for (int j = 0; j < 8; ++j) {
      float4 v = *(const float4*)(src + j * 16);
      *(float4*)(cL + ldsc((unsigned)r, (unsigned)(part * 128 + j * 16))) = v;
    }
  }
  if (tid < Kk) tabL[tid] = tab[tid];
  __syncthreads();

  const int b   = blockIdx.x >> 5;     // 32 batches x 32 segments
  const int seg = blockIdx.x & 31;
  const int nrow = seg * 128 + w * 16 + ln;            // row within batch
  const float* xrow = x + ((size_t)b * Nn + nrow) * Dd;

  f32x4 s1[8];
  const f32x4 zero4 = {0.f, 0.f, 0.f, 0.f};
  #pragma unroll
  for (int f = 0; f < 8; ++f) s1[f] = zero4;
  float x2p = 0.f;

  // distance-4 rotating prefetch (32 payload VGPRs)
  float4 pu[4][2];
  #pragma unroll
  for (int p = 0; p < 4; ++p) {
    pu[p][0] = *(const float4*)(xrow + p * 32 + g * 8);
    pu[p][1] = *(const float4*)(xrow + p * 32 + g * 8 + 4);
  }
  __builtin_amdgcn_sched_barrier(0);   // pin the 8 prologue loads before any use

  #pragma unroll
  for (int ks = 0; ks < 8; ++ks) {
    float4 u0 = pu[ks & 3][0], u1 = pu[ks & 3][1];
    if (ks + 4 < 8) {
      pu[ks & 3][0] = *(const float4*)(xrow + (ks + 4) * 32 + g * 8);
      pu[ks & 3][1] = *(const float4*)(xrow + (ks + 4) * 32 + g * 8 + 4);
    }
    x2p += u0.x*u0.x + u0.y*u0.y + u0.z*u0.z + u0.w*u0.w
         + u1.x*u1.x + u1.y*u1.y + u1.z*u1.z + u1.w*u1.w;
    bf16x8 xv;
    xv[0] = (short)f2bf(u0.x); xv[1] = (short)f2bf(u0.y);
    xv[2] = (short)f2bf(u0.z); xv[3] = (short)f2bf(u0.w);
    xv[4] = (short)f2bf(u1.x); xv[5] = (short)f2bf(u1.y);
    xv[6] = (short)f2bf(u1.z); xv[7] = (short)f2bf(u1.w);
    const unsigned colb = (unsigned)(ks * 64 + g * 16);
    #pragma unroll
    for (int f = 0; f < 8; ++f) {
      bf16x8 a = *(const bf16x8*)(cL + ldsc((unsigned)(f * 16 + ln), colb));
      s1[f] = __builtin_amdgcn_mfma_f32_16x16x32_bf16(a, xv, s1[f], 0, 0, 0);
    }
    __builtin_amdgcn_sched_barrier(0); // iteration boundary: reloads stay put
  }

  x2p += __shfl_xor(x2p, 16); x2p += __shfl_xor(x2p, 32);
  const float hx2 = 0.5f * x2p;
  float ssum = 0.f;
  #pragma unroll
  for (int f = 0; f < 8; ++f) {
    #pragma unroll
    for (int r = 0; r < 4; ++r) {
      const float2 ab = tabL[f * 16 + g * 4 + r];
      const float ev = __expf(ab.x + ab.y * (hx2 - s1[f][r]));
      s1[f][r] = ev;
      ssum += ev;
    }
  }
  ssum += __shfl_xor(ssum, 16); ssum += __shfl_xor(ssum, 32);
  const float rinv = 1.0f / ssum;

  // transpose W through LDS (reuse cL: all cbf reads are done)
  __syncthreads();
  #pragma unroll
  for (int f = 0; f < 8; ++f) {
    #pragma unroll
    for (int r = 0; r < 4; ++r) {
      const int cwi = f * 16 + g * 4 + r;
      *(unsigned short*)(cL + ldsw((unsigned)cwi, (unsigned)((w * 16 + ln) * 2)))
          = f2bf(s1[f][r] * rinv);
    }
  }
  __syncthreads();
  // coalesced store: instr j covers local tile bytes tid*16 + j*8192
  {
    char* wq = (char*)(Wt + (size_t)b * Kk * Nn + seg * 128);
    #pragma unroll
    for (int j = 0; j < 4; ++j) {
      const unsigned o = (unsigned)tid * 16u + (unsigned)j * 8192u;
      const unsigned k = o >> 8, nb = o & 255u;
      float4 v = *(const float4*)(cL + ldsw(k, nb));
      *(float4*)(wq + (size_t)k * (Nn * 2) + nb) = v;
    }
  }
}

// ---------------- k1b: Wsumg[b][k] = sum_n Wt[b][k][n]. One wave per (b,k)
// row; Wt is L2/L3-hot from enc_w. 1024 blocks x 4 waves, fully coalesced.
__global__ __launch_bounds__(256, 1) void enc_wsum(
    const unsigned short* __restrict__ Wt, float* __restrict__ Wsumg) {
  const int w = threadIdx.x >> 6, l = threadIdx.x & 63;
  const int row = blockIdx.x * 4 + w;          // b*Kk + k
  const unsigned short* p = Wt + (size_t)row * Nn + l * 8;
  float s = 0.f;
  #pragma unroll
  for (int j = 0; j < 8; ++j) {
    ushort4 v0 = *(const ushort4*)(p + j * 512);
    ushort4 v1 = *(const ushort4*)(p + j * 512 + 4);
    s += bf2f(v0.x) + bf2f(v0.y) + bf2f(v0.z) + bf2f(v0.w)
       + bf2f(v1.x) + bf2f(v1.y) + bf2f(v1.z) + bf2f(v1.w);
  }
  #pragma unroll
  for (int o = 1; o < 64; o <<= 1) s += __shfl_xor(s, o);
  if (l == 0) Wsumg[row] = s;
}

// ---------------- k2: Ep_chunk[k][d] = sum_n W^T[k][n] x[n][d]  (raw partials;
// the -Wsum*c correction is applied once in the reduce). Double-buffered LDS xT,
// issue-early/write-late staging, W frags prefetched one step ahead.
template<int PM>
__global__ __launch_bounds__(1024) void enc_e(
    const float* __restrict__ x, const unsigned short* __restrict__ Wt,
    unsigned short* __restrict__ Ep, float* __restrict__ out) {
  __shared__ __align__(16) char xs[2 * 32768];   // xT [256 d][64 n] bf16, dbuf

  const int tid = threadIdx.x;
  const int w  = tid >> 6;             // wave 0..15
  const int l  = tid & 63;
  const int g  = l >> 4;
  const int ln = l & 15;
  const int wr = w >> 2, wc = w & 3;   // 4x4 wave grid over E(128k x 256d)
  const int b  = blockIdx.x >> 3, ch = blockIdx.x & 7;

  const float* xb = x + ((size_t)b * Nn + ch * NCH) * Dd;
  const unsigned short* Wb = Wt + (size_t)b * Kk * Nn + ch * NCH;

  // staging role: row n_loc = w*4+g (0..63), d-slice = ln*16..+15 (16 floats)
  const int srow = w * 4 + g;
  const int sd0  = ln * 16;

  f32x4 acc[2][4];
  const f32x4 zero4 = {0.f, 0.f, 0.f, 0.f};
  #pragma unroll
  for (int mi = 0; mi < 2; ++mi)
    #pragma unroll
    for (int ni = 0; ni < 4; ++ni) acc[mi][ni] = zero4;

  // prologue: stage step 0 into buf 0; prefetch step 0's W frags
  {
    const float* p = xb + (size_t)srow * Dd + sd0;
    float4 u0 = *(const float4*)(p + 0), u1 = *(const float4*)(p + 4);
    float4 u2 = *(const float4*)(p + 8), u3 = *(const float4*)(p + 12);
    const float uu[16] = {u0.x,u0.y,u0.z,u0.w, u1.x,u1.y,u1.z,u1.w,
                          u2.x,u2.y,u2.z,u2.w, u3.x,u3.y,u3.z,u3.w};
    #pragma unroll
    for (int j = 0; j < 16; ++j)
      *(unsigned short*)(xs + lds2((unsigned)(sd0 + j), (unsigned)(srow * 2))) = f2bf(uu[j]);
  }
  bf16x8 wf[2][2];   // [ks2][mi] current step's W fragments
  #pragma unroll
  for (int ks2 = 0; ks2 < 2; ++ks2)
    #pragma unroll
    for (int mi = 0; mi < 2; ++mi)
      wf[ks2][mi] = *(const bf16x8*)(Wb + (size_t)(wr * 32 + mi * 16 + ln) * Nn
                                        + ks2 * 32 + g * 8);
  __syncthreads();

  int cur = 0;
  for (int s = 0; s < CH2; ++s) {          // 8 n-steps of 64
    // issue next step's x loads AND W-frag loads before compute
    float4 n0, n1, n2, n3;
    bf16x8 wn[2][2];
    if (s + 1 < CH2) {
      const float* p = xb + (size_t)((s + 1) * NSTEP + srow) * Dd + sd0;
      n0 = *(const float4*)(p + 0); n1 = *(const float4*)(p + 4);
      n2 = *(const float4*)(p + 8); n3 = *(const float4*)(p + 12);
      #pragma unroll
      for (int ks2 = 0; ks2 < 2; ++ks2)
        #pragma unroll
        for (int mi = 0; mi < 2; ++mi)
          wn[ks2][mi] = *(const bf16x8*)(Wb + (size_t)(wr * 32 + mi * 16 + ln) * Nn
                                            + (s + 1) * NSTEP + ks2 * 32 + g * 8);
    }

    const char* xcur = xs + (cur << 15);
    #pragma unroll
    for (int ks2 = 0; ks2 < 2; ++ks2) {
      bf16x8 bg[4];
      #pragma unroll
      for (int ni = 0; ni < 4; ++ni)
        bg[ni] = *(const bf16x8*)(xcur + lds2((unsigned)(wc * 64 + ni * 16 + ln),
                                              (unsigned)((ks2 * 32 + g * 8) * 2)));
      #pragma unroll
      for (int mi = 0; mi < 2; ++mi)
        #pragma unroll
        for (int ni = 0; ni < 4; ++ni)
          acc[mi][ni] = __builtin_amdgcn_mfma_f32_16x16x32_bf16(wf[ks2][mi], bg[ni], acc[mi][ni], 0, 0, 0);
    }

    if (s + 1 < CH2) {
      // write-late: LDS writes to the opposite buffer (no reader this step)
      char* xn = xs + ((cur ^ 1) << 15);
      const float uu[16] = {n0.x,n0.y,n0.z,n0.w, n1.x,n1.y,n1.z,n1.w,
                            n2.x,n2.y,n2.z,n2.w, n3.x,n3.y,n3.z,n3.w};
      #pragma unroll
      for (int j = 0; j < 16; ++j)
        *(unsigned short*)(xn + lds2((unsigned)(sd0 + j), (unsigned)(srow * 2))) = f2bf(uu[j]);
      #pragma unroll
      for (int ks2 = 0; ks2 < 2; ++ks2)
        #pragma unroll
        for (int mi = 0; mi < 2; ++mi)
          wf[ks2][mi] = wn[ks2][mi];
    }
    __syncthreads();   // single barrier per step
    cur ^= 1;
  }

  // epilogue: bare bf16 partial store (correction applied in reduce)
  #pragma unroll
  for (int mi = 0; mi < 2; ++mi) {
    #pragma unroll
    for (int r = 0; r < 4; ++r) {
      const int k = wr * 32 + mi * 16 + g * 4 + r;
      #pragma unroll
      for (int ni = 0; ni < 4; ++ni) {
        const int d = wc * 64 + ni * 16 + ln;
        if (PM == 0) {
          Ep[(size_t)blockIdx.x * (Kk * Dd) + k * Dd + d] = f2bf(acc[mi][ni][r]);
        } else {
          atomicAdd(out + (size_t)b * (Kk * Dd) + k * Dd + d, acc[mi][ni][r]);
        }
      }
    }
  }
}

// ---------------- k3: out = sum over 8 bf16 chunk-partials - Wsum[b][k]*cw[k][d]
__global__ __launch_bounds__(256, 1) void enc_reduce_b16(
    const unsigned short* __restrict__ Ep, const float* __restrict__ Wsumg,
    const float* __restrict__ cw, float* __restrict__ out) {
  const size_t i = ((size_t)blockIdx.x * 256 + threadIdx.x) * 16;
  const int b   = (int)(i / (Kk * Dd));
  const int rem = (int)(i % (Kk * Dd));
  const int k   = rem >> 8;                       // Dd = 256
  const unsigned short* p = Ep + (size_t)b * CH2 * (Kk * Dd) + rem;
  const float wsv = Wsumg[b * Kk + k];
  float sx[16];
  #pragma unroll
  for (int j = 0; j < 16; ++j) sx[j] = 0.f;
  #pragma unroll
  for (int c = 0; c < CH2; ++c) {
    const ushort4* q = (const ushort4*)(p + (size_t)c * (Kk * Dd));
    ushort4 v0 = q[0], v1 = q[1], v2 = q[2], v3 = q[3];
    sx[0]  += bf2f(v0.x); sx[1]  += bf2f(v0.y); sx[2]  += bf2f(v0.z); sx[3]  += bf2f(v0.w);
    sx[4]  += bf2f(v1.x); sx[5]  += bf2f(v1.y); sx[6]  += bf2f(v1.z); sx[7]  += bf2f(v1.w);
    sx[8]  += bf2f(v2.x); sx[9]  += bf2f(v2.y); sx[10] += bf2f(v2.z); sx[11] += bf2f(v2.w);
    sx[12] += bf2f(v3.x); sx[13] += bf2f(v3.y); sx[14] += bf2f(v3.z); sx[15] += bf2f(v3.w);
  }
  const float* cp = cw + (size_t)rem;
  float4 c0 = *(const float4*)(cp + 0), c1 = *(const float4*)(cp + 4);
  float4 c2 = *(const float4*)(cp + 8), c3 = *(const float4*)(cp + 12);
  float4* o = (float4*)(out + i);
  o[0] = make_float4(sx[0] - wsv * c0.x, sx[1] - wsv * c0.y, sx[2] - wsv * c0.z, sx[3] - wsv * c0.w);
  o[1] = make_float4(sx[4] - wsv * c1.x, sx[5] - wsv * c1.y, sx[6] - wsv * c1.z, sx[7] - wsv * c1.w);
  o[2] = make_float4(sx[8] - wsv * c2.x, sx[9] - wsv * c2.y, sx[10] - wsv * c2.z, sx[11] - wsv * c2.w);
  o[3] = make_float4(sx[12] - wsv * c3.x, sx[13] - wsv * c3.y, sx[14] - wsv * c3.z, sx[15] - wsv * c3.w);
}

// fallback-path fixup: out[i] -= Wsum[b][k]*cw[k][d]
__global__ __launch_bounds__(256, 1) void enc_fix(
    const float* __restrict__ Wsumg, const float* __restrict__ cw,
    float* __restrict__ out) {
  const size_t i = ((size_t)blockIdx.x * 256 + threadIdx.x) * 16;
  const int b   = (int)(i / (Kk * Dd));
  const int rem = (int)(i % (Kk * Dd));
  const int k   = rem >> 8;
  const float wsv = Wsumg[b * Kk + k];
  float* o = out + i;
  const float* cp = cw + (size_t)rem;
  #pragma unroll
  for (int j = 0; j < 16; ++j) o[j] -= wsv * cp[j];
}

extern "C" void kernel_launch(void* const* d_in, const int* in_sizes, int n_in,
                              void* d_out, int out_size, void* d_ws, size_t ws_size,
                              hipStream_t stream) {
  const float* x  = (const float*)d_in[0];   // (32, 4096, 256)
  const float* cw = (const float*)d_in[1];   // (128, 256)
  const float* sc = (const float*)d_in[2];   // (128,)
  float* out = (float*)d_out;                // (32, 128, 256)

  unsigned short* cbf = (unsigned short*)d_ws;                      // 64KB
  float2* tab = (float2*)((char*)d_ws + 65536);                     // 1KB
  float*  Wsumg = (float*)((char*)d_ws + 66560);                    // 16KB [b][k]
  unsigned short* Wt = (unsigned short*)((char*)d_ws + 82944);      // 33.55MB W^T bf16
  unsigned short* Ep = (unsigned short*)((char*)d_ws + 82944 + (size_t)32 * Kk * Nn * 2); // 16.8MB bf16
  const size_t KD = (size_t)Kk * Dd;
  const size_t needFull = 82944 + (size_t)32 * Kk * Nn * 2 + (size_t)32 * CH2 * KD * 2;
  const size_t needAtm  = 82944 + (size_t)32 * Kk * Nn * 2;

  enc_prep<<<dim3(Kk), dim3(64), 0, stream>>>(cw, sc, cbf, tab);
  enc_w<<<dim3(32 * SEGS), dim3(512), 0, stream>>>(x, cbf, tab, Wt);
  enc_wsum<<<dim3((32 * Kk) / 4), dim3(256), 0, stream>>>(Wt, Wsumg);

  if (ws_size >= needFull) {
    enc_e<0><<<dim3(32 * CH2), dim3(1024), 0, stream>>>(x, Wt, Ep, nullptr);
    enc_reduce_b16<<<dim3(256), dim3(256), 0, stream>>>(Ep, Wsumg, cw, out);
  } else if (ws_size >= needAtm) {
    hipMemsetAsync(d_out, 0, (size_t)out_size * sizeof(float), stream);
    enc_e<2><<<dim3(32 * CH2), dim3(1024), 0, stream>>>(x, Wt, nullptr, out);
    enc_fix<<<dim3(256), dim3(256), 0, stream>>>(Wsumg, cw, out);
  }
}